// Round 4
// baseline (8262.737 us; speedup 1.0000x reference)
//
#include <hip/hip_runtime.h>

#define NB 128      // batch
#define NT 512      // time steps
#define DIN 256     // layer-0 input dim
#define DD 512      // hidden dim

using bf16x8 = __attribute__((ext_vector_type(8))) short;
using f32x4v = __attribute__((ext_vector_type(4))) float;
using u32x4  = __attribute__((ext_vector_type(4))) unsigned int;

__device__ __forceinline__ unsigned short f2bf(float f) {
  unsigned int u = __builtin_bit_cast(unsigned int, f);
  u = (u + 0x7fffu + ((u >> 16) & 1u)) >> 16;
  return (unsigned short)u;
}
__device__ __forceinline__ float bf2f(unsigned short h) {
  unsigned int u = ((unsigned int)h) << 16;
  return __builtin_bit_cast(float, u);
}
// pack fp32 -> (bf16 hi | bf16 lo) in one dword: split-bf16 keeps the 512-step recurrence accurate
__device__ __forceinline__ unsigned int packf(float v) {
  unsigned short hi = f2bf(v);
  unsigned short lo = f2bf(v - bf2f(hi));
  return (((unsigned int)hi) << 16) | lo;
}

// ---------------- prep: pack x, zero state parities & flag lines ----------------
__global__ void prep_kernel(const float* __restrict__ x, unsigned int* __restrict__ x_pk,
                            unsigned int* __restrict__ hp, unsigned int* __restrict__ cnt) {
  long i = (long)blockIdx.x * blockDim.x + threadIdx.x;
  const long stride = (long)gridDim.x * blockDim.x;
  const long NX = (long)NB * NT * DIN;
  for (long j = i; j < NX; j += stride) x_pk[j] = packf(x[j]);
  const long NH = 2L * 2 * NB * DD;              // [parity][layer][row][col]
  for (long j = i; j < NH; j += stride) hp[j] = 0u;
  if (i < 4096) cnt[i] = 0u;                     // 4 groups x 64 flag lines (ws poisoned 0xAA)
}

__device__ __forceinline__ void unpack16(const u32x4& q0, const u32x4& q1,
                                         bf16x8& hi, bf16x8& lo) {
  #pragma unroll
  for (int j = 0; j < 4; ++j) {
    hi[j]     = (short)(q0[j] >> 16);
    lo[j]     = (short)(q0[j] & 0xffffu);
    hi[4 + j] = (short)(q1[j] >> 16);
    lo[4 + j] = (short)(q1[j] & 0xffffu);
  }
}

// Streaming K-partial GEMM (register-light; lesson r1/r2: cross-barrier register state spills).
// One output tile: 4 MFMA chains (2 k-streams x hi/lo).
template<int KN>
__device__ __forceinline__ void gemm_pk(const unsigned int* __restrict__ a,
                                        const unsigned short* __restrict__ b,
                                        int quad, f32x4v& cH0, f32x4v& cL0,
                                        f32x4v& cH1, f32x4v& cL1) {
  const unsigned int* ap = a + quad * 8;
  const unsigned short* bp = b + quad * 8;
  #pragma unroll
  for (int kk = 0; kk < KN; kk += 64) {
    u32x4 q0 = *(const u32x4*)(ap + kk);
    u32x4 q1 = *(const u32x4*)(ap + kk + 4);
    u32x4 q2 = *(const u32x4*)(ap + kk + 32);
    u32x4 q3 = *(const u32x4*)(ap + kk + 36);
    bf16x8 a0h, a0l, a1h, a1l;
    unpack16(q0, q1, a0h, a0l);
    unpack16(q2, q3, a1h, a1l);
    bf16x8 b0 = *(const bf16x8*)(bp + kk);
    bf16x8 b1 = *(const bf16x8*)(bp + kk + 32);
    cH0 = __builtin_amdgcn_mfma_f32_16x16x32_bf16(a0h, b0, cH0, 0, 0, 0);
    cL0 = __builtin_amdgcn_mfma_f32_16x16x32_bf16(a0l, b0, cL0, 0, 0, 0);
    cH1 = __builtin_amdgcn_mfma_f32_16x16x32_bf16(a1h, b1, cH1, 0, 0, 0);
    cL1 = __builtin_amdgcn_mfma_f32_16x16x32_bf16(a1l, b1, cL1, 0, 0, 0);
  }
}

// Fused z+r GEMM: ONE A stream feeds TWO B column-segments (8 accumulators). Halves the
// phase-A A-operand L2 traffic vs the old z-wave/r-wave duplicate reads.
template<int KN>
__device__ __forceinline__ void gemm_pk2(const unsigned int* __restrict__ a,
                                         const unsigned short* __restrict__ b0,
                                         const unsigned short* __restrict__ b1,
                                         int quad,
                                         f32x4v& zH0, f32x4v& zL0, f32x4v& zH1, f32x4v& zL1,
                                         f32x4v& rH0, f32x4v& rL0, f32x4v& rH1, f32x4v& rL1) {
  const unsigned int* ap = a + quad * 8;
  const unsigned short* b0p = b0 + quad * 8;
  const unsigned short* b1p = b1 + quad * 8;
  #pragma unroll
  for (int kk = 0; kk < KN; kk += 64) {
    u32x4 q0 = *(const u32x4*)(ap + kk);
    u32x4 q1 = *(const u32x4*)(ap + kk + 4);
    u32x4 q2 = *(const u32x4*)(ap + kk + 32);
    u32x4 q3 = *(const u32x4*)(ap + kk + 36);
    bf16x8 a0h, a0l, a1h, a1l;
    unpack16(q0, q1, a0h, a0l);
    unpack16(q2, q3, a1h, a1l);
    bf16x8 bz0 = *(const bf16x8*)(b0p + kk);
    bf16x8 bz1 = *(const bf16x8*)(b0p + kk + 32);
    bf16x8 br0 = *(const bf16x8*)(b1p + kk);
    bf16x8 br1 = *(const bf16x8*)(b1p + kk + 32);
    zH0 = __builtin_amdgcn_mfma_f32_16x16x32_bf16(a0h, bz0, zH0, 0, 0, 0);
    zL0 = __builtin_amdgcn_mfma_f32_16x16x32_bf16(a0l, bz0, zL0, 0, 0, 0);
    rH0 = __builtin_amdgcn_mfma_f32_16x16x32_bf16(a0h, br0, rH0, 0, 0, 0);
    rL0 = __builtin_amdgcn_mfma_f32_16x16x32_bf16(a0l, br0, rL0, 0, 0, 0);
    zH1 = __builtin_amdgcn_mfma_f32_16x16x32_bf16(a1h, bz1, zH1, 0, 0, 0);
    zL1 = __builtin_amdgcn_mfma_f32_16x16x32_bf16(a1l, bz1, zL1, 0, 0, 0);
    rH1 = __builtin_amdgcn_mfma_f32_16x16x32_bf16(a1h, br1, rH1, 0, 0, 0);
    rL1 = __builtin_amdgcn_mfma_f32_16x16x32_bf16(a1l, br1, rL1, 0, 0, 0);
  }
}

// Flag barrier over 64 WGs (both layers, one rb group).
// Release: __syncthreads drains vmcnt(0) (write-through atomic data stores complete) -> ONE
// plain relaxed store of the round number to this WG's OWN 64B flag line (no RMW contention).
// Wait: wave 0 polls all 64 flags with a single 64-lane atomic load (LLC-coherent) + __all.
// Then ONE acquire load -> buffer_inv so post-barrier plain loads see fresh data.
__device__ __forceinline__ void gbarrier(unsigned int* gf, int slot, int w, int lane,
                                         unsigned int rnd) {
  __syncthreads();
  if (threadIdx.x == 0)
    __hip_atomic_store(gf + slot * 16, rnd, __ATOMIC_RELAXED, __HIP_MEMORY_SCOPE_AGENT);
  if (w == 0) {
    for (;;) {
      unsigned int v = __hip_atomic_load(gf + lane * 16, __ATOMIC_RELAXED,
                                         __HIP_MEMORY_SCOPE_AGENT);
      if (__all((int)(v >= rnd))) break;
      __builtin_amdgcn_s_sleep(1);
    }
    if (lane == 0)
      (void)__hip_atomic_load(gf, __ATOMIC_ACQUIRE, __HIP_MEMORY_SCOPE_AGENT);
  }
  __syncthreads();
}

// ---------------- persistent GRU ----------------
// 256 WGs x 256 thr, 1 WG/CU. WG (l, rb, cb) owns rows [32rb,32rb+32), h/z/r cols
// [16cb,16cb+16) of layer l. 4 independent rb-groups of 64 WGs; 2 flag barriers/super-step.
// XCD swizzle (r4): dispatch round-robins bid%8 across the 8 XCDs, so decode (l,rb) from
// bid&7 and cb from bid>>3 -> each (l,rb) group's 32 WGs land on ONE XCD and share their
// A-panel via that XCD's L2 after the post-barrier invalidate (LLC traffic /~30).
__global__ void __launch_bounds__(256, 1) gru_kernel(
    const float* __restrict__ Wzr0, const float* __restrict__ bzr0,
    const float* __restrict__ Wh0,  const float* __restrict__ bh0,
    const float* __restrict__ Wzr1, const float* __restrict__ bzr1,
    const float* __restrict__ Wh1,  const float* __restrict__ bh1,
    const unsigned int* __restrict__ x_pk, unsigned int* __restrict__ hp,
    unsigned int* __restrict__ zs, unsigned int* __restrict__ cnt,
    float* __restrict__ out)
{
  extern __shared__ __align__(16) unsigned char smem[];
  const int bid = blockIdx.x, tid = threadIdx.x;
  const int w = tid >> 6, lane = tid & 63, quad = lane >> 4, l16 = lane & 15;
  const int g  = bid & 7;           // XCD id (dispatch round-robin assumption)
  const int l  = g >> 2;            // layer
  const int rb = g & 3;             // row block (sync group)
  const int cb = bid >> 3;          // column block
  const int r0 = rb << 5;
  const int c0 = cb << 4;
  const int K  = l ? 1024 : 768;
  const int KI = l ? 512 : 256;     // input-part K (x for L0, h0 for L1)
  const int ldw = K + 8;            // +8 shorts padding

  unsigned short* wlds = (unsigned short*)smem;                 // [48 cols][ldw]: z(16) r(16) h(16)
  float* s_lds = (float*)(smem + ((48 * ldw * 2 + 15) & ~15));  // [32][16] fp32 master state
  float* r_lds = s_lds + 512;                                   // [32][16] r gate
  float* pscr  = r_lds + 512;                                   // [1024] partial-sum scratch

  const float* Wzr = l ? Wzr1 : Wzr0;
  const float* Wh  = l ? Wh1 : Wh0;
  for (int idx = tid; idx < 16 * K; idx += 256) {
    int j = idx / K, k = idx - j * K;
    wlds[j * ldw + k]        = f2bf(Wzr[k * (2 * DD) + c0 + j]);        // z cols
    wlds[(16 + j) * ldw + k] = f2bf(Wzr[k * (2 * DD) + DD + c0 + j]);   // r cols
    wlds[(32 + j) * ldw + k] = f2bf(Wh[k * DD + c0 + j]);               // h cols
  }
  for (int idx = tid; idx < 512; idx += 256) s_lds[idx] = 0.f;
  const float bz = (l ? bzr1 : bzr0)[c0 + l16];
  const float br = (l ? bzr1 : bzr0)[DD + c0 + l16];
  const float bh = (l ? bh1 : bh0)[c0 + l16];
  __syncthreads();

  unsigned int* gf = cnt + rb * 1024;  // this group's 64 flag lines (64B apart)
  const int slot = l * 32 + cb;
  unsigned int rnd = 0;

  for (int s = 0; s <= NT; ++s) {
    const int p  = (s + 1) & 1;        // read parity
    const int pw = s & 1;              // write parity
    const bool act = l ? (s >= 1) : (s < NT);
    const int t = l ? (s - 1) : s;

    // ===== phase A (fused z+r): one A stream per wave, waves split by K-source =====
    // wave w: rowHalf = w>>1, seg = w&1 (seg0: input-K part; seg1: recurrence-K part).
    if (act) {
      const int rowHalf = w >> 1, seg = w & 1;
      const int gRow = r0 + (rowHalf << 4) + l16;
      f32x4v zH0 = {0,0,0,0}, zL0 = {0,0,0,0}, zH1 = {0,0,0,0}, zL1 = {0,0,0,0};
      f32x4v rH0 = {0,0,0,0}, rL0 = {0,0,0,0}, rH1 = {0,0,0,0}, rL1 = {0,0,0,0};
      const unsigned short* bzseg = wlds + l16 * ldw;
      const unsigned short* brseg = wlds + (16 + l16) * ldw;
      if (l == 0) {
        if (seg == 0) {
          const unsigned int* xa = x_pk + ((long)gRow * NT + t) * DIN;
          gemm_pk2<256>(xa, bzseg, brseg, quad, zH0, zL0, zH1, zL1, rH0, rL0, rH1, rL1);
        } else {
          const unsigned int* ha = hp + ((p * 2 + 0) * NB + gRow) * DD;
          gemm_pk2<512>(ha, bzseg + 256, brseg + 256, quad,
                        zH0, zL0, zH1, zL1, rH0, rL0, rH1, rL1);
        }
      } else {
        if (seg == 0) {
          const unsigned int* h0a = hp + ((p * 2 + 0) * NB + gRow) * DD;
          gemm_pk2<512>(h0a, bzseg, brseg, quad, zH0, zL0, zH1, zL1, rH0, rL0, rH1, rL1);
        } else {
          const unsigned int* h1a = hp + ((p * 2 + 1) * NB + gRow) * DD;
          gemm_pk2<512>(h1a, bzseg + 512, brseg + 512, quad,
                        zH0, zL0, zH1, zL1, rH0, rL0, rH1, rL1);
        }
      }
      float zt[4], rt[4];
      #pragma unroll
      for (int i = 0; i < 4; ++i) {
        zt[i] = (zH0[i] + zL0[i]) + (zH1[i] + zL1[i]);
        rt[i] = (rH0[i] + rL0[i]) + (rH1[i] + rL1[i]);
      }
      if (seg == 1) {
        #pragma unroll
        for (int i = 0; i < 4; ++i) {
          pscr[rowHalf * 512 + ((quad << 2) + i) * 16 + l16]       = zt[i];
          pscr[rowHalf * 512 + 256 + ((quad << 2) + i) * 16 + l16] = rt[i];
        }
      }
      __syncthreads();   // act is WG-uniform -> legal
      if (seg == 0) {
        #pragma unroll
        for (int i = 0; i < 4; ++i) {
          int rloc = (rowHalf << 4) + (quad << 2) + i;
          float zpre = zt[i] + pscr[rowHalf * 512 + ((quad << 2) + i) * 16 + l16] + bz;
          float rpre = rt[i] + pscr[rowHalf * 512 + 256 + ((quad << 2) + i) * 16 + l16] + br;
          float zg = 1.f / (1.f + __expf(-zpre));
          float rg = 1.f / (1.f + __expf(-rpre));
          float sv = s_lds[rloc * 16 + l16];
          __hip_atomic_store(&zs[((long)l * NB + r0 + rloc) * DD + c0 + l16],
                             packf(zg * sv), __ATOMIC_RELAXED, __HIP_MEMORY_SCOPE_AGENT);
          r_lds[rloc * 16 + l16] = rg;
        }
      }
    }
    ++rnd;
    gbarrier(gf, slot, w, lane, rnd);

    // ============ phase B: h = r*s + (1-r)*tanh([in | z*s] Wh + b) ============
    if (act) {
      const int rowHalf = w & 1, src = w >> 1;   // waves 0,1: input-K; 2,3: zs-K
      const int gRow = r0 + (rowHalf << 4) + l16;
      f32x4v cH0 = {0,0,0,0}, cL0 = {0,0,0,0}, cH1 = {0,0,0,0}, cL1 = {0,0,0,0};
      const unsigned short* hseg = wlds + (32 + l16) * ldw;
      if (src == 0) {
        if (l == 0) {
          const unsigned int* xa = x_pk + ((long)gRow * NT + t) * DIN;
          gemm_pk<256>(xa, hseg, quad, cH0, cL0, cH1, cL1);
        } else {
          const unsigned int* h0a = hp + ((p * 2 + 0) * NB + gRow) * DD;
          gemm_pk<512>(h0a, hseg, quad, cH0, cL0, cH1, cL1);
        }
      } else {
        const unsigned int* za = zs + ((long)l * NB + gRow) * DD;
        gemm_pk<512>(za, hseg + KI, quad, cH0, cL0, cH1, cL1);
      }
      f32x4v tot;
      #pragma unroll
      for (int i = 0; i < 4; ++i) tot[i] = (cH0[i] + cL0[i]) + (cH1[i] + cL1[i]);
      if (src == 1) {
        #pragma unroll
        for (int i = 0; i < 4; ++i)
          pscr[rowHalf * 256 + ((quad << 2) + i) * 16 + l16] = tot[i];
      }
      __syncthreads();   // act is WG-uniform -> legal
      if (src == 0) {
        #pragma unroll
        for (int i = 0; i < 4; ++i) {
          int rloc = (rowHalf << 4) + (quad << 2) + i;
          float pre = tot[i] + pscr[rowHalf * 256 + ((quad << 2) + i) * 16 + l16] + bh;
          float ax = fabsf(pre), e = __expf(-2.f * ax);
          float th = (1.f - e) / (1.f + e);
          th = (pre < 0.f) ? -th : th;
          float rv = r_lds[rloc * 16 + l16];
          float sv = s_lds[rloc * 16 + l16];
          float h = rv * sv + (1.f - rv) * th;
          s_lds[rloc * 16 + l16] = h;
          __hip_atomic_store(&hp[((pw * 2 + l) * NB + r0 + rloc) * DD + c0 + l16],
                             packf(h), __ATOMIC_RELAXED, __HIP_MEMORY_SCOPE_AGENT);
          if (l) out[((long)(r0 + rloc) * NT + t) * DD + c0 + l16] = h;
        }
      }
    }
    ++rnd;
    gbarrier(gf, slot, w, lane, rnd);
  }
}

// ---------------- host ----------------
extern "C" void kernel_launch(void* const* d_in, const int* in_sizes, int n_in,
                              void* d_out, int out_size, void* d_ws, size_t ws_size,
                              hipStream_t stream) {
  const float* x    = (const float*)d_in[0];
  const float* Wzr0 = (const float*)d_in[1];
  const float* bzr0 = (const float*)d_in[2];
  const float* Wh0  = (const float*)d_in[3];
  const float* bh0  = (const float*)d_in[4];
  const float* Wzr1 = (const float*)d_in[5];
  const float* bzr1 = (const float*)d_in[6];
  const float* Wh1  = (const float*)d_in[7];
  const float* bh1  = (const float*)d_in[8];
  float* out = (float*)d_out;

  char* pp = (char*)d_ws;
  unsigned int* cnt  = (unsigned int*)pp;  pp += 16384;                      // 4 x 64 flag lines
  unsigned int* x_pk = (unsigned int*)pp;  pp += (size_t)NB * NT * DIN * 4;  // packed hi|lo
  unsigned int* hp   = (unsigned int*)pp;  pp += (size_t)2 * 2 * NB * DD * 4;
  unsigned int* zs   = (unsigned int*)pp;  pp += (size_t)2 * NB * DD * 4;

  hipLaunchKernelGGL(prep_kernel, dim3(1024), dim3(256), 0, stream, x, x_pk, hp, cnt);

  const int SMEM = ((48 * (1024 + 8) * 2 + 15) & ~15) + 2 * 512 * 4 + 1024 * 4;  // 107264 B
  (void)hipFuncSetAttribute((const void*)gru_kernel,
                            hipFuncAttributeMaxDynamicSharedMemorySize, SMEM);
  // 256 WGs x 256 thr, >80 KB LDS each -> exactly 1 WG/CU, all co-resident (no deadlock)
  hipLaunchKernelGGL(gru_kernel, dim3(256), dim3(256), SMEM, stream,
                     Wzr0, bzr0, Wh0, bh0, Wzr1, bzr1, Wh1, bh1,
                     x_pk, hp, zs, cnt, out);
}

// Round 5
// 6836.834 us; speedup vs baseline: 1.2086x; 1.2086x over previous
//
#include <hip/hip_runtime.h>

#define NB 128      // batch
#define NT 512      // time steps
#define DIN 256     // layer-0 input dim
#define DD 512      // hidden dim

using bf16x8 = __attribute__((ext_vector_type(8))) short;
using f32x4v = __attribute__((ext_vector_type(4))) float;
using u32x4  = __attribute__((ext_vector_type(4))) unsigned int;

__device__ __forceinline__ unsigned short f2bf(float f) {
  unsigned int u = __builtin_bit_cast(unsigned int, f);
  u = (u + 0x7fffu + ((u >> 16) & 1u)) >> 16;
  return (unsigned short)u;
}
__device__ __forceinline__ float bf2f(unsigned short h) {
  unsigned int u = ((unsigned int)h) << 16;
  return __builtin_bit_cast(float, u);
}
// pack fp32 -> (bf16 hi | bf16 lo) in one dword: split-bf16 keeps the 512-step recurrence accurate
__device__ __forceinline__ unsigned int packf(float v) {
  unsigned short hi = f2bf(v);
  unsigned short lo = f2bf(v - bf2f(hi));
  return (((unsigned int)hi) << 16) | lo;
}

// ---------------- prep: pack x, zero state parities & flag lines ----------------
__global__ void prep_kernel(const float* __restrict__ x, unsigned int* __restrict__ x_pk,
                            unsigned int* __restrict__ hp, unsigned int* __restrict__ cnt) {
  long i = (long)blockIdx.x * blockDim.x + threadIdx.x;
  const long stride = (long)gridDim.x * blockDim.x;
  const long NX = (long)NB * NT * DIN;
  for (long j = i; j < NX; j += stride) x_pk[j] = packf(x[j]);
  const long NH = 2L * 2 * NB * DD;              // [parity][layer][row][col]
  for (long j = i; j < NH; j += stride) hp[j] = 0u;
  if (i < 4096) cnt[i] = 0u;                     // 4 groups x 64 flag lines (ws poisoned 0xAA)
}

__device__ __forceinline__ void unpack16(const u32x4& q0, const u32x4& q1,
                                         bf16x8& hi, bf16x8& lo) {
  #pragma unroll
  for (int j = 0; j < 4; ++j) {
    hi[j]     = (short)(q0[j] >> 16);
    lo[j]     = (short)(q0[j] & 0xffffu);
    hi[4 + j] = (short)(q1[j] >> 16);
    lo[4 + j] = (short)(q1[j] & 0xffffu);
  }
}

// Streaming K-partial GEMM (register-light; lesson r1/r2: cross-barrier register state spills).
template<int KN>
__device__ __forceinline__ void gemm_pk(const unsigned int* __restrict__ a,
                                        const unsigned short* __restrict__ b,
                                        int quad, f32x4v& cH0, f32x4v& cL0,
                                        f32x4v& cH1, f32x4v& cL1) {
  const unsigned int* ap = a + quad * 8;
  const unsigned short* bp = b + quad * 8;
  #pragma unroll
  for (int kk = 0; kk < KN; kk += 64) {
    u32x4 q0 = *(const u32x4*)(ap + kk);
    u32x4 q1 = *(const u32x4*)(ap + kk + 4);
    u32x4 q2 = *(const u32x4*)(ap + kk + 32);
    u32x4 q3 = *(const u32x4*)(ap + kk + 36);
    bf16x8 a0h, a0l, a1h, a1l;
    unpack16(q0, q1, a0h, a0l);
    unpack16(q2, q3, a1h, a1l);
    bf16x8 b0 = *(const bf16x8*)(bp + kk);
    bf16x8 b1 = *(const bf16x8*)(bp + kk + 32);
    cH0 = __builtin_amdgcn_mfma_f32_16x16x32_bf16(a0h, b0, cH0, 0, 0, 0);
    cL0 = __builtin_amdgcn_mfma_f32_16x16x32_bf16(a0l, b0, cL0, 0, 0, 0);
    cH1 = __builtin_amdgcn_mfma_f32_16x16x32_bf16(a1h, b1, cH1, 0, 0, 0);
    cL1 = __builtin_amdgcn_mfma_f32_16x16x32_bf16(a1l, b1, cL1, 0, 0, 0);
  }
}

// Fused z+r GEMM: ONE A stream feeds TWO B column-segments (8 accumulators).
template<int KN>
__device__ __forceinline__ void gemm_pk2(const unsigned int* __restrict__ a,
                                         const unsigned short* __restrict__ b0,
                                         const unsigned short* __restrict__ b1,
                                         int quad,
                                         f32x4v& zH0, f32x4v& zL0, f32x4v& zH1, f32x4v& zL1,
                                         f32x4v& rH0, f32x4v& rL0, f32x4v& rH1, f32x4v& rL1) {
  const unsigned int* ap = a + quad * 8;
  const unsigned short* b0p = b0 + quad * 8;
  const unsigned short* b1p = b1 + quad * 8;
  #pragma unroll
  for (int kk = 0; kk < KN; kk += 64) {
    u32x4 q0 = *(const u32x4*)(ap + kk);
    u32x4 q1 = *(const u32x4*)(ap + kk + 4);
    u32x4 q2 = *(const u32x4*)(ap + kk + 32);
    u32x4 q3 = *(const u32x4*)(ap + kk + 36);
    bf16x8 a0h, a0l, a1h, a1l;
    unpack16(q0, q1, a0h, a0l);
    unpack16(q2, q3, a1h, a1l);
    bf16x8 bz0 = *(const bf16x8*)(b0p + kk);
    bf16x8 bz1 = *(const bf16x8*)(b0p + kk + 32);
    bf16x8 br0 = *(const bf16x8*)(b1p + kk);
    bf16x8 br1 = *(const bf16x8*)(b1p + kk + 32);
    zH0 = __builtin_amdgcn_mfma_f32_16x16x32_bf16(a0h, bz0, zH0, 0, 0, 0);
    zL0 = __builtin_amdgcn_mfma_f32_16x16x32_bf16(a0l, bz0, zL0, 0, 0, 0);
    rH0 = __builtin_amdgcn_mfma_f32_16x16x32_bf16(a0h, br0, rH0, 0, 0, 0);
    rL0 = __builtin_amdgcn_mfma_f32_16x16x32_bf16(a0l, br0, rL0, 0, 0, 0);
    zH1 = __builtin_amdgcn_mfma_f32_16x16x32_bf16(a1h, bz1, zH1, 0, 0, 0);
    zL1 = __builtin_amdgcn_mfma_f32_16x16x32_bf16(a1l, bz1, zL1, 0, 0, 0);
    rH1 = __builtin_amdgcn_mfma_f32_16x16x32_bf16(a1h, br1, rH1, 0, 0, 0);
    rL1 = __builtin_amdgcn_mfma_f32_16x16x32_bf16(a1l, br1, rL1, 0, 0, 0);
  }
}

// Flag barrier over 64 WGs (both layers, one rb group). See r3 comments.
__device__ __forceinline__ void gbarrier(unsigned int* gf, int slot, int w, int lane,
                                         unsigned int rnd) {
  __syncthreads();
  if (threadIdx.x == 0)
    __hip_atomic_store(gf + slot * 16, rnd, __ATOMIC_RELAXED, __HIP_MEMORY_SCOPE_AGENT);
  if (w == 0) {
    for (;;) {
      unsigned int v = __hip_atomic_load(gf + lane * 16, __ATOMIC_RELAXED,
                                         __HIP_MEMORY_SCOPE_AGENT);
      if (__all((int)(v >= rnd))) break;
      __builtin_amdgcn_s_sleep(1);
    }
    if (lane == 0)
      (void)__hip_atomic_load(gf, __ATOMIC_ACQUIRE, __HIP_MEMORY_SCOPE_AGENT);
  }
  __syncthreads();
}

// ---------------- persistent GRU ----------------
// r5: 256 WGs x 512 thr (8 waves) = 2 waves/SIMD for latency hiding (r3 had 1/SIMD, 12.4%
// occupancy, phases latency-bound). K split 4 ways per row-half; 3-partial LDS reduction.
// r4's XCD swizzle reverted (FETCH dropped 4x but time +10% -> locality was a non-problem).
__global__ void __launch_bounds__(512, 1) gru_kernel(
    const float* __restrict__ Wzr0, const float* __restrict__ bzr0,
    const float* __restrict__ Wh0,  const float* __restrict__ bh0,
    const float* __restrict__ Wzr1, const float* __restrict__ bzr1,
    const float* __restrict__ Wh1,  const float* __restrict__ bh1,
    const unsigned int* __restrict__ x_pk, unsigned int* __restrict__ hp,
    unsigned int* __restrict__ zs, unsigned int* __restrict__ cnt,
    float* __restrict__ out)
{
  extern __shared__ __align__(16) unsigned char smem[];
  const int bid = blockIdx.x, tid = threadIdx.x;
  const int w = tid >> 6, lane = tid & 63, quad = lane >> 4, l16 = lane & 15;
  const int l  = bid >> 7;          // layer
  const int rb = (bid >> 5) & 3;    // row block (sync group)
  const int cb = bid & 31;          // column block
  const int r0 = rb << 5;
  const int c0 = cb << 4;
  const int K  = l ? 1024 : 768;
  const int ldw = K + 8;            // +8 shorts padding

  unsigned short* wlds = (unsigned short*)smem;                 // [48 cols][ldw]: z(16) r(16) h(16)
  float* s_lds = (float*)(smem + ((48 * ldw * 2 + 15) & ~15));  // [32][16] fp32 master state
  float* r_lds = s_lds + 512;                                   // [32][16] r gate
  float* pscr  = r_lds + 512;                                   // [3072] partial-sum scratch

  const float* Wzr = l ? Wzr1 : Wzr0;
  const float* Wh  = l ? Wh1 : Wh0;
  for (int idx = tid; idx < 16 * K; idx += 512) {
    int j = idx / K, k = idx - j * K;
    wlds[j * ldw + k]        = f2bf(Wzr[k * (2 * DD) + c0 + j]);        // z cols
    wlds[(16 + j) * ldw + k] = f2bf(Wzr[k * (2 * DD) + DD + c0 + j]);   // r cols
    wlds[(32 + j) * ldw + k] = f2bf(Wh[k * DD + c0 + j]);               // h cols
  }
  for (int idx = tid; idx < 512; idx += 512) s_lds[idx] = 0.f;
  const float bz = (l ? bzr1 : bzr0)[c0 + l16];
  const float br = (l ? bzr1 : bzr0)[DD + c0 + l16];
  const float bh = (l ? bh1 : bh0)[c0 + l16];
  __syncthreads();

  unsigned int* gf = cnt + rb * 1024;  // this group's 64 flag lines (64B apart)
  const int slot = l * 32 + cb;
  unsigned int rnd = 0;

  const int rowHalf = w >> 2, seg = w & 3;   // 2 row-halves x 4 K-segments
  const int gRow = r0 + (rowHalf << 4) + l16;
  const int pidx = (quad << 2) * 16 + l16;   // +i*16 per accum elem

  for (int s = 0; s <= NT; ++s) {
    const int p  = (s + 1) & 1;        // read parity
    const int pw = s & 1;              // write parity
    const bool act = l ? (s >= 1) : (s < NT);
    const int t = l ? (s - 1) : s;

    // ===== phase A (fused z+r): K split 4 ways: L0 {x256|h192|h192|h128}, L1 {256x4} =====
    if (act) {
      f32x4v zH0 = {0,0,0,0}, zL0 = {0,0,0,0}, zH1 = {0,0,0,0}, zL1 = {0,0,0,0};
      f32x4v rH0 = {0,0,0,0}, rL0 = {0,0,0,0}, rH1 = {0,0,0,0}, rL1 = {0,0,0,0};
      const unsigned short* bzseg = wlds + l16 * ldw;
      const unsigned short* brseg = wlds + (16 + l16) * ldw;
      if (l == 0) {
        const unsigned int* xa = x_pk + ((long)gRow * NT + t) * DIN;
        const unsigned int* ha = hp + ((p * 2 + 0) * NB + gRow) * DD;
        if      (seg == 0) gemm_pk2<256>(xa, bzseg, brseg, quad,
                                         zH0, zL0, zH1, zL1, rH0, rL0, rH1, rL1);
        else if (seg == 1) gemm_pk2<192>(ha, bzseg + 256, brseg + 256, quad,
                                         zH0, zL0, zH1, zL1, rH0, rL0, rH1, rL1);
        else if (seg == 2) gemm_pk2<192>(ha + 192, bzseg + 448, brseg + 448, quad,
                                         zH0, zL0, zH1, zL1, rH0, rL0, rH1, rL1);
        else               gemm_pk2<128>(ha + 384, bzseg + 640, brseg + 640, quad,
                                         zH0, zL0, zH1, zL1, rH0, rL0, rH1, rL1);
      } else {
        const unsigned int* h0a = hp + ((p * 2 + 0) * NB + gRow) * DD;
        const unsigned int* h1a = hp + ((p * 2 + 1) * NB + gRow) * DD;
        if      (seg == 0) gemm_pk2<256>(h0a, bzseg, brseg, quad,
                                         zH0, zL0, zH1, zL1, rH0, rL0, rH1, rL1);
        else if (seg == 1) gemm_pk2<256>(h0a + 256, bzseg + 256, brseg + 256, quad,
                                         zH0, zL0, zH1, zL1, rH0, rL0, rH1, rL1);
        else if (seg == 2) gemm_pk2<256>(h1a, bzseg + 512, brseg + 512, quad,
                                         zH0, zL0, zH1, zL1, rH0, rL0, rH1, rL1);
        else               gemm_pk2<256>(h1a + 256, bzseg + 768, brseg + 768, quad,
                                         zH0, zL0, zH1, zL1, rH0, rL0, rH1, rL1);
      }
      float zt[4], rt[4];
      #pragma unroll
      for (int i = 0; i < 4; ++i) {
        zt[i] = (zH0[i] + zL0[i]) + (zH1[i] + zL1[i]);
        rt[i] = (rH0[i] + rL0[i]) + (rH1[i] + rL1[i]);
      }
      if (seg) {   // pscr layout: [rowHalf][seg-1][z|r][256]
        float* pp = pscr + rowHalf * 1536 + (seg - 1) * 512;
        #pragma unroll
        for (int i = 0; i < 4; ++i) {
          pp[pidx + i * 16]       = zt[i];
          pp[256 + pidx + i * 16] = rt[i];
        }
      }
      __syncthreads();   // act is WG-uniform -> legal
      if (seg == 0) {
        const float* pp = pscr + rowHalf * 1536;
        #pragma unroll
        for (int i = 0; i < 4; ++i) {
          int rloc = (rowHalf << 4) + (quad << 2) + i;
          float zpre = zt[i] + pp[pidx + i * 16] + pp[512 + pidx + i * 16]
                     + pp[1024 + pidx + i * 16] + bz;
          float rpre = rt[i] + pp[256 + pidx + i * 16] + pp[768 + pidx + i * 16]
                     + pp[1280 + pidx + i * 16] + br;
          float zg = 1.f / (1.f + __expf(-zpre));
          float rg = 1.f / (1.f + __expf(-rpre));
          float sv = s_lds[rloc * 16 + l16];
          __hip_atomic_store(&zs[((long)l * NB + r0 + rloc) * DD + c0 + l16],
                             packf(zg * sv), __ATOMIC_RELAXED, __HIP_MEMORY_SCOPE_AGENT);
          r_lds[rloc * 16 + l16] = rg;
        }
      }
    }
    ++rnd;
    gbarrier(gf, slot, w, lane, rnd);

    // ===== phase B: h = r*s + (1-r)*tanh([in | z*s] Wh + b); K split 4 ways =====
    if (act) {
      f32x4v cH0 = {0,0,0,0}, cL0 = {0,0,0,0}, cH1 = {0,0,0,0}, cL1 = {0,0,0,0};
      const unsigned short* hseg = wlds + (32 + l16) * ldw;
      if (l == 0) {
        const unsigned int* xa = x_pk + ((long)gRow * NT + t) * DIN;
        const unsigned int* za = zs + ((long)l * NB + gRow) * DD;
        if      (seg == 0) gemm_pk<256>(xa, hseg, quad, cH0, cL0, cH1, cL1);
        else if (seg == 1) gemm_pk<192>(za, hseg + 256, quad, cH0, cL0, cH1, cL1);
        else if (seg == 2) gemm_pk<192>(za + 192, hseg + 448, quad, cH0, cL0, cH1, cL1);
        else               gemm_pk<128>(za + 384, hseg + 640, quad, cH0, cL0, cH1, cL1);
      } else {
        const unsigned int* h0a = hp + ((p * 2 + 0) * NB + gRow) * DD;
        const unsigned int* za = zs + ((long)l * NB + gRow) * DD;
        if      (seg == 0) gemm_pk<256>(h0a, hseg, quad, cH0, cL0, cH1, cL1);
        else if (seg == 1) gemm_pk<256>(h0a + 256, hseg + 256, quad, cH0, cL0, cH1, cL1);
        else if (seg == 2) gemm_pk<256>(za, hseg + 512, quad, cH0, cL0, cH1, cL1);
        else               gemm_pk<256>(za + 256, hseg + 768, quad, cH0, cL0, cH1, cL1);
      }
      f32x4v tot;
      #pragma unroll
      for (int i = 0; i < 4; ++i) tot[i] = (cH0[i] + cL0[i]) + (cH1[i] + cL1[i]);
      if (seg) {   // pscr layout: [rowHalf][seg-1][256]
        float* pp = pscr + rowHalf * 768 + (seg - 1) * 256;
        #pragma unroll
        for (int i = 0; i < 4; ++i) pp[pidx + i * 16] = tot[i];
      }
      __syncthreads();   // act is WG-uniform -> legal
      if (seg == 0) {
        const float* pp = pscr + rowHalf * 768;
        #pragma unroll
        for (int i = 0; i < 4; ++i) {
          int rloc = (rowHalf << 4) + (quad << 2) + i;
          float pre = tot[i] + pp[pidx + i * 16] + pp[256 + pidx + i * 16]
                    + pp[512 + pidx + i * 16] + bh;
          float ax = fabsf(pre), e = __expf(-2.f * ax);
          float th = (1.f - e) / (1.f + e);
          th = (pre < 0.f) ? -th : th;
          float rv = r_lds[rloc * 16 + l16];
          float sv = s_lds[rloc * 16 + l16];
          float h = rv * sv + (1.f - rv) * th;
          s_lds[rloc * 16 + l16] = h;
          __hip_atomic_store(&hp[((pw * 2 + l) * NB + r0 + rloc) * DD + c0 + l16],
                             packf(h), __ATOMIC_RELAXED, __HIP_MEMORY_SCOPE_AGENT);
          if (l) out[((long)(r0 + rloc) * NT + t) * DD + c0 + l16] = h;
        }
      }
    }
    ++rnd;
    gbarrier(gf, slot, w, lane, rnd);
  }
}

// ---------------- host ----------------
extern "C" void kernel_launch(void* const* d_in, const int* in_sizes, int n_in,
                              void* d_out, int out_size, void* d_ws, size_t ws_size,
                              hipStream_t stream) {
  const float* x    = (const float*)d_in[0];
  const float* Wzr0 = (const float*)d_in[1];
  const float* bzr0 = (const float*)d_in[2];
  const float* Wh0  = (const float*)d_in[3];
  const float* bh0  = (const float*)d_in[4];
  const float* Wzr1 = (const float*)d_in[5];
  const float* bzr1 = (const float*)d_in[6];
  const float* Wh1  = (const float*)d_in[7];
  const float* bh1  = (const float*)d_in[8];
  float* out = (float*)d_out;

  char* pp = (char*)d_ws;
  unsigned int* cnt  = (unsigned int*)pp;  pp += 16384;                      // 4 x 64 flag lines
  unsigned int* x_pk = (unsigned int*)pp;  pp += (size_t)NB * NT * DIN * 4;  // packed hi|lo
  unsigned int* hp   = (unsigned int*)pp;  pp += (size_t)2 * 2 * NB * DD * 4;
  unsigned int* zs   = (unsigned int*)pp;  pp += (size_t)2 * NB * DD * 4;

  hipLaunchKernelGGL(prep_kernel, dim3(1024), dim3(256), 0, stream, x, x_pk, hp, cnt);

  // weights 48*(1024+8)*2 = 99072 B + s_lds 2048 + r_lds 2048 + pscr 12288 = 115456 B
  const int SMEM = ((48 * (1024 + 8) * 2 + 15) & ~15) + 2 * 512 * 4 + 3072 * 4;
  (void)hipFuncSetAttribute((const void*)gru_kernel,
                            hipFuncAttributeMaxDynamicSharedMemorySize, SMEM);
  // 256 WGs x 512 thr, >80 KB LDS each -> exactly 1 WG/CU, all co-resident (no deadlock)
  hipLaunchKernelGGL(gru_kernel, dim3(256), dim3(512), SMEM, stream,
                     Wzr0, bzr0, Wh0, bh0, Wzr1, bzr1, Wh1, bh1,
                     x_pk, hp, zs, cnt, out);
}